// Round 12
// baseline (281.193 us; speedup 1.0000x reference)
//
#include <hip/hip_runtime.h>
#include <stdint.h>

// Problem constants
#define BB 4
#define TT 2048
#define CC 1024
#define HH 16
#define DH 64
#define NQKV 3072

typedef __bf16 bf16_t;
typedef __attribute__((ext_vector_type(8))) __bf16 bf16x8;
typedef __attribute__((ext_vector_type(4))) __bf16 bf16x4;
typedef __attribute__((ext_vector_type(4))) float f32x4;

#define MFMA16(a, b, c) __builtin_amdgcn_mfma_f32_16x16x32_bf16((a), (b), (c), 0, 0, 0)

// async global->LDS, 16B per lane. LDS dest = wave-uniform base + lane*16.
__device__ __forceinline__ void gll16(const void* g, void* l) {
  typedef const __attribute__((address_space(1))) void* gp_t;
  typedef __attribute__((address_space(3))) void* lp_t;
  __builtin_amdgcn_global_load_lds((gp_t)(uintptr_t)g, (lp_t)(uintptr_t)l, 16, 0, 0);
}

__device__ __forceinline__ void cvt8(const float* src, bf16_t* dst) {
  const f32x4 a = *(const f32x4*)(src);
  const f32x4 b = *(const f32x4*)(src + 4);
  bf16x8 r;
  r[0] = (bf16_t)a[0]; r[1] = (bf16_t)a[1]; r[2] = (bf16_t)a[2]; r[3] = (bf16_t)a[3];
  r[4] = (bf16_t)b[0]; r[5] = (bf16_t)b[1]; r[6] = (bf16_t)b[2]; r[7] = (bf16_t)b[3];
  *(bf16x8*)dst = r;
}

// ---------------------------------------------------------------------------
// fp32 -> bf16 converts (n multiples of 2048)
// ---------------------------------------------------------------------------
__global__ __launch_bounds__(256) void cvt_k(const float* __restrict__ src,
                                             bf16_t* __restrict__ dst, int n) {
  const int i8 = (blockIdx.x * 256 + threadIdx.x) * 8;
  if (i8 < n) cvt8(src + i8, dst + i8);
}

__global__ __launch_bounds__(256) void cvt2_k(const float* __restrict__ s0,
                                              bf16_t* __restrict__ d0, int n0,
                                              const float* __restrict__ s1,
                                              bf16_t* __restrict__ d1, int n1) {
  int i8 = (blockIdx.x * 256 + threadIdx.x) * 8;
  if (i8 < n0) { cvt8(s0 + i8, d0 + i8); return; }
  i8 -= n0;
  if (i8 < n1) cvt8(s1 + i8, d1 + i8);
}

// three independent arrays, one launch (kernel-count reduction)
__global__ __launch_bounds__(256) void cvt3_k(
    const float* __restrict__ s0, bf16_t* __restrict__ d0, int n0,
    const float* __restrict__ s1, bf16_t* __restrict__ d1, int n1,
    const float* __restrict__ s2, bf16_t* __restrict__ d2, int n2) {
  int i8 = (blockIdx.x * 256 + threadIdx.x) * 8;
  if (i8 < n0) { cvt8(s0 + i8, d0 + i8); return; }
  i8 -= n0;
  if (i8 < n1) { cvt8(s1 + i8, d1 + i8); return; }
  i8 -= n1;
  if (i8 < n2) cvt8(s2 + i8, d2 + i8);
}

// ---------------------------------------------------------------------------
// GEMM (bf16 A, bf16 W): C[m][n] = sum_k A[m][k]*W[n][k] (+bias[n]); K=1024.
// R11-verified kernel (273.5us total). Session bracketing: deeper pipeline
// (R6), bigger tile (R1), persistence (R10) ALL regress vs this structure.
//   stage-ahead 2-phase: issue next BK=32 step's 4 gll16 into buf^1 BEFORE
//   computing buf[cur]; single vmcnt(0)+s_barrier after the compute phase
//   (drain sits a full compute phase after issue; cross-block TLP covers it).
//   XCD-chunked + within-XCD 4x4 supertile remap (FETCH 84->62MB, R7->R8).
// LDS XOR-swizzled: logical (row r, chunk cc) at slot r*4 + (cc ^ (r&3));
// gather permutes the per-lane global source.
// EPI==0: qkv epilogue (RoPE Q/K, 0.125*log2e folded into Q, scatter B,H,T,dh)
// EPI==1: bias epilogue into fp32 out0
// ---------------------------------------------------------------------------
template <int EPI>
__global__ __launch_bounds__(256) void gemm_k(
    const bf16_t* __restrict__ A, const bf16_t* __restrict__ W,
    const float* __restrict__ bias,
    const float* __restrict__ fcos, const float* __restrict__ fsin,
    void* __restrict__ out0v, bf16_t* __restrict__ out1,
    bf16_t* __restrict__ out2) {
  __shared__ bf16_t Alds[2][128 * 32];  // [dbuf][128 rows x 32 k]
  __shared__ bf16_t Blds[2][128 * 32];
  const int K = 1024;
  const int tid = threadIdx.x;
  const int lane = tid & 63, wave = tid >> 6;
  const int quad = lane >> 4, c = lane & 15;
  const int wm = wave >> 1, wn = wave & 1;

  // XCD-chunked + within-XCD 4x4 supertile remap (requires nx%4==0 and
  // (cpx/nx)%4==0; holds for both launches: 24x64 and 8x64).
  const int nx = gridDim.x;
  const int d = blockIdx.y * nx + blockIdx.x;  // dispatch order (x fastest)
  const int cpx = (nx * gridDim.y) >> 3;
  const int xcd = d & 7, j = d >> 3;
  const int nyl = cpx / nx;        // by-rows per XCD (8 in both gemms)
  const int stpr = nx >> 2;        // supertiles along bx
  const int st = j >> 4, wi = j & 15;
  const int bx = (st % stpr) * 4 + (wi & 3);
  const int by = xcd * nyl + (st / stpr) * 4 + (wi >> 2);
  const int mbase = by * 128, nbase = bx * 128;

  f32x4 acc[4][4];
#pragma unroll
  for (int i = 0; i < 4; ++i)
#pragma unroll
    for (int j2 = 0; j2 < 4; ++j2) acc[i][j2] = (f32x4){0.f, 0.f, 0.f, 0.f};

  // permuted gather: slot s=tid (+256) holds logical (r=s>>2, cc=(s&3)^(r&3))
  const int s0 = tid, s1 = tid + 256;
  const int r0 = s0 >> 2, cc0 = (s0 & 3) ^ (r0 & 3);
  const int r1 = s1 >> 2, cc1 = (s1 & 3) ^ (r1 & 3);
  const bf16_t* ag0 = A + (mbase + r0) * K + cc0 * 8;
  const bf16_t* ag1 = A + (mbase + r1) * K + cc1 * 8;
  const bf16_t* bg0 = W + (nbase + r0) * K + cc0 * 8;
  const bf16_t* bg1 = W + (nbase + r1) * K + cc1 * 8;

#define GSTAGE(BUF, KO)                        \
  {                                            \
    gll16(ag0 + (KO), &Alds[BUF][s0 * 8]);     \
    gll16(ag1 + (KO), &Alds[BUF][s1 * 8]);     \
    gll16(bg0 + (KO), &Blds[BUF][s0 * 8]);     \
    gll16(bg1 + (KO), &Blds[BUF][s1 * 8]);     \
  }

// One BK=32 step. CUR is a literal 0/1; STG gates stage+barrier (off on the
// final step). Stage for step KS+1 goes into buf CUR^1 (its readers finished
// before the previous step's barrier).
#define GSTEP(KS, CUR, STG)                                                    \
  {                                                                            \
    if (STG) GSTAGE((CUR) ^ 1, ((KS) + 1) * 32);                               \
    bf16x8 af[4], bfr[4];                                                      \
    _Pragma("unroll") for (int mi = 0; mi < 4; ++mi) {                         \
      const int row = wm * 64 + mi * 16 + c;                                   \
      af[mi] = *(const bf16x8*)&Alds[CUR][(row * 4 + (quad ^ (row & 3))) * 8]; \
    }                                                                          \
    _Pragma("unroll") for (int ni = 0; ni < 4; ++ni) {                         \
      const int row = wn * 64 + ni * 16 + c;                                   \
      bfr[ni] =                                                                \
          *(const bf16x8*)&Blds[CUR][(row * 4 + (quad ^ (row & 3))) * 8];      \
    }                                                                          \
    _Pragma("unroll") for (int mi = 0; mi < 4; ++mi)                           \
        _Pragma("unroll") for (int ni = 0; ni < 4; ++ni)                       \
            acc[mi][ni] = MFMA16(af[mi], bfr[ni], acc[mi][ni]);                \
    if (STG) {                                                                 \
      asm volatile("s_waitcnt vmcnt(0)" ::: "memory");                         \
      __builtin_amdgcn_s_barrier();                                            \
      asm volatile("" ::: "memory");                                           \
    }                                                                          \
  }

  // prologue: stage step 0, drain, barrier
  GSTAGE(0, 0);
  asm volatile("s_waitcnt vmcnt(0)" ::: "memory");
  __builtin_amdgcn_s_barrier();
  asm volatile("" ::: "memory");

  // steps 0..29 (15 unrolled pairs), then 30 (stages 31), then 31 (no stage)
  for (int fj = 0; fj < 15; ++fj) {
    GSTEP(2 * fj, 0, 1)
    GSTEP(2 * fj + 1, 1, 1)
  }
  GSTEP(30, 0, 1)
  GSTEP(31, 1, 0)
#undef GSTEP
#undef GSTAGE

  // epilogue. C/D layout: col = lane&15 (+16*ni), row = quad*4 + r (+16*mi)
  const float qscale = 0.18033688011112042f;  // 0.125 * log2(e)
#pragma unroll
  for (int mi = 0; mi < 4; ++mi) {
#pragma unroll
    for (int ni = 0; ni < 4; ++ni) {
      const int n = nbase + wn * 64 + ni * 16 + c;
      const float bv = bias[n];
#pragma unroll
      for (int r = 0; r < 4; ++r) {
        const int m = mbase + wm * 64 + mi * 16 + quad * 4 + r;
        float v = acc[mi][ni][r] + bv;
        if (EPI == 0) {
          bf16_t* out0 = (bf16_t*)out0v;
          const int sel = n >> 10;  // 0=q 1=k 2=v
          const int nl = n & 1023;
          const int h = nl >> 6, dd = nl & 63;
          const int b = m >> 11, t = m & 2047;
          const int dst = ((b * HH + h) * TT + t) * DH + dd;
          if (sel < 2) {
            const float pv = __shfl_xor(v, 1, 64);  // RoPE partner (col n^1)
            const int d2 = dd >> 1;
            const float cs = fcos[t * 32 + d2];
            const float sn = fsin[t * 32 + d2];
            float o = ((dd & 1) == 0) ? (v * cs - pv * sn) : (pv * sn + v * cs);
            if (sel == 0) {
              o *= qscale;
              out0[dst] = (bf16_t)o;
            } else {
              out1[dst] = (bf16_t)o;
            }
          } else {
            out2[dst] = (bf16_t)v;
          }
        } else {
          float* outf = (float*)out0v;
          outf[m * CC + n] = v;
        }
      }
    }
  }
}

// ---------------------------------------------------------------------------
// Flash attention, causal. Q pre-scaled by 0.125*log2(e) (exp2 domain).
// R5-verified structure (swapped QK^T, XCD swizzle, defer-max, no setprio).
// R12 chain-shortening (both numerics-identical):
//  (1) speculative exp2: pf = exp2(s - m_s) hoisted BEFORE the rescale
//      branch (doesn't depend on the max tree in the common path); the rare
//      rescale branch RECOMPUTES pf with the updated m_s -> bit-identical
//      values in both paths, but the 2 tree-shuffles now overlap the exp2s.
//  (2) in-register rowsum: scalar l_s (S^T layout, replicated across quads
//      via 2 shfl_xor) replaces the 2 rowsum MFMAs that sat AFTER the LDS
//      round-trip on the chain; rescale is a scalar mult; write_O fetches
//      1/l via 4 shuffles. PV is now the only consumer of the LDS read.
// ---------------------------------------------------------------------------
__global__ __launch_bounds__(256, 4) void attn_k(const bf16_t* __restrict__ Q,
                                                 const bf16_t* __restrict__ Kv,
                                                 const bf16_t* __restrict__ V,
                                                 bf16_t* __restrict__ O) {
  __shared__ bf16_t KS[2][64 * 64];
  __shared__ bf16_t VtS[2][64 * 64];
  __shared__ bf16_t PS[4][16 * 64];

  const int tid = threadIdx.x;
  const int lane = tid & 63, wave = tid >> 6;
  const int quad = lane >> 4, c = lane & 15;
  // XCD-chunked bijective swizzle: 1024 blocks = 8 XCDs x 128; each XCD gets
  // 8 complete (b,h) groups -> 4 MB K/V working set = its L2.
  const int d0 = blockIdx.x;
  const int bi = (d0 & 7) * 128 + (d0 >> 3);
  const int pair = bi & 15, h = (bi >> 4) & 15, b = bi >> 8;
  const int qtA = pair, qtB = 31 - pair;
  const int nA = qtA + 1;  // kv tiles in phase A

  const bf16_t* Qh = Q + ((b * HH + h) * TT) * DH;
  const bf16_t* Kh = Kv + ((b * HH + h) * TT) * DH;
  const bf16_t* Vh = V + ((b * HH + h) * TT) * DH;

  const f32x4 zero4 = {0.f, 0.f, 0.f, 0.f};

  // staging bases (per-thread, loop-invariant)
  const int krow0 = tid >> 3, kc8 = tid & 7, krow1 = krow0 + 32;
  const bf16_t* kbase0 = Kh + krow0 * DH + kc8 * 8;
  const bf16_t* kbase1 = Kh + krow1 * DH + kc8 * 8;
  const int vsb = tid >> 2, vjp = tid & 3;
  const int vrg = vsb & 7, vc8 = vsb >> 3;
  const int vd0 = vc8 * 8 + vjp * 2, vd1 = vd0 + 1;
  const bf16_t* vbase = Vh + vrg * 8 * DH + vd0;

  // invariant swizzled fragment offsets (elements): row c, chunk (quad|quad+4)
  const int sw = c & 7;
  const int e0 = c * 64 + (quad ^ sw) * 8;
  const int e1 = c * 64 + ((quad + 4) ^ sw) * 8;

  bf16x8 kr0, kr1;
  uint32_t vr[8];
  auto load_tile = [&](int eoff) {
    kr0 = *(const bf16x8*)(kbase0 + eoff);
    kr1 = *(const bf16x8*)(kbase1 + eoff);
    const bf16_t* vp = vbase + eoff;
#pragma unroll
    for (int i = 0; i < 8; ++i) vr[i] = *(const uint32_t*)(vp + i * DH);
  };
  auto store_tile = [&](int buf) {
    *(bf16x8*)&KS[buf][(krow0 * 8 + (kc8 ^ (krow0 & 7))) * 8] = kr0;
    *(bf16x8*)&KS[buf][(krow1 * 8 + (kc8 ^ (krow1 & 7))) * 8] = kr1;
    union { bf16x8 v; uint16_t u[8]; } colA, colB;
#pragma unroll
    for (int i = 0; i < 8; ++i) {
      colA.u[i] = (uint16_t)(vr[i] & 0xffffu);
      colB.u[i] = (uint16_t)(vr[i] >> 16);
    }
    *(bf16x8*)&VtS[buf][(vd0 * 8 + (vrg ^ (vd0 & 7))) * 8] = colA.v;
    *(bf16x8*)&VtS[buf][(vd1 * 8 + (vrg ^ (vd1 & 7))) * 8] = colB.v;
  };

  // phase state (A first)
  int qtbase = qtA * 64;
  bf16x8 qf0 = *(const bf16x8*)(Qh + (qtbase + wave * 16 + c) * DH + quad * 8);
  bf16x8 qf1 = *(const bf16x8*)(Qh + (qtbase + wave * 16 + c) * DH + 32 + quad * 8);

  f32x4 o_acc[4] = {zero4, zero4, zero4, zero4};
  float m_s = -1e30f;  // running max for q-row c (S^T layout)
  float l_s = 0.f;     // rowsum for q-row c (replicated across quads)

  auto write_O = [&](int qtb) {
#pragma unroll
    for (int r = 0; r < 4; ++r) {
      const int qg = qtb + wave * 16 + quad * 4 + r;
      const float lq = __shfl(l_s, (lane & 48) | (quad * 4 + r), 64);
      const float inv = 1.0f / lq;
#pragma unroll
      for (int ni = 0; ni < 4; ++ni)
        O[(b * TT + qg) * CC + h * 64 + ni * 16 + c] =
            (bf16_t)(o_acc[ni][r] * inv);
    }
  };

  load_tile(0);
  store_tile(0);
  __syncthreads();
  int coff = 0;   // current tile element offset into K/V
  int kkey = 0;   // current tile key-index base

// one kv iteration; CUR is a literal 0/1 -> LDS addresses fold to constants
#define ATTN_ITER(FI, CUR)                                                     \
  {                                                                            \
    const int fi_ = (FI);                                                      \
    const bool pre_ = fi_ < 32;                                                \
    const int noff_ = (fi_ + 1 == nA) ? 0 : coff + 64 * DH;                    \
    if (pre_) load_tile(noff_);                                                \
    bf16x8 kf0[4], kf1[4];                                                     \
    _Pragma("unroll") for (int ni = 0; ni < 4; ++ni) {                         \
      kf0[ni] = *(const bf16x8*)&KS[CUR][ni * 1024 + e0];                      \
      kf1[ni] = *(const bf16x8*)&KS[CUR][ni * 1024 + e1];                      \
    }                                                                          \
    /* swapped: s[ni][r] = S[q = qtbase+wave*16+c][kv = kkey+ni*16+quad*4+r] */\
    f32x4 s[4];                                                                \
    _Pragma("unroll") for (int ni = 0; ni < 4; ++ni) {                         \
      f32x4 t = MFMA16(kf0[ni], qf0, zero4);                                   \
      t = MFMA16(kf1[ni], qf1, t);                                             \
      s[ni] = t;                                                               \
    }                                                                          \
    const int minq_ = qtbase + wave * 16;                                      \
    if (kkey + 63 > minq_) {                                                   \
      const int qg_ = minq_ + c;                                               \
      _Pragma("unroll") for (int ni = 0; ni < 4; ++ni)                         \
          _Pragma("unroll") for (int r = 0; r < 4; ++r) {                      \
        const int key_ = kkey + ni * 16 + quad * 4 + r;                        \
        if (key_ > qg_) s[ni][r] = -1e30f;                                     \
      }                                                                        \
    }                                                                          \
    /* speculative exp2 (common path: m_s unchanged -> these are final) */     \
    float pf[4][4];                                                            \
    _Pragma("unroll") for (int ni = 0; ni < 4; ++ni)                           \
        _Pragma("unroll") for (int r = 0; r < 4; ++r)                          \
            pf[ni][r] = __builtin_amdgcn_exp2f(s[ni][r] - m_s);                \
    /* row max (overlaps the exp2s): in-register tree + 2 quad shuffles */     \
    float a0_ = fmaxf(fmaxf(s[0][0], s[0][1]), fmaxf(s[0][2], s[0][3]));       \
    float a1_ = fmaxf(fmaxf(s[1][0], s[1][1]), fmaxf(s[1][2], s[1][3]));       \
    float a2_ = fmaxf(fmaxf(s[2][0], s[2][1]), fmaxf(s[2][2], s[2][3]));       \
    float a3_ = fmaxf(fmaxf(s[3][0], s[3][1]), fmaxf(s[3][2], s[3][3]));       \
    float mx = fmaxf(fmaxf(a0_, a1_), fmaxf(a2_, a3_));                        \
    mx = fmaxf(mx, __shfl_xor(mx, 16, 64));                                    \
    mx = fmaxf(mx, __shfl_xor(mx, 32, 64));                                    \
    /* defer-max (T13): rescale only if some row-max grew by >8; rare path    \
       RECOMPUTES pf with the new m_s (bit-identical to non-speculative) */    \
    if (__any(mx > m_s + 8.0f)) {                                              \
      const float mnew = fmaxf(m_s, mx);                                       \
      const float al = __builtin_amdgcn_exp2f(m_s - mnew);                     \
      m_s = mnew;                                                              \
      l_s *= al;                                                               \
      _Pragma("unroll") for (int ni = 0; ni < 4; ++ni)                         \
          _Pragma("unroll") for (int r = 0; r < 4; ++r)                        \
              pf[ni][r] = __builtin_amdgcn_exp2f(s[ni][r] - m_s);              \
      _Pragma("unroll") for (int r = 0; r < 4; ++r) {                          \
        const float alD = __shfl(al, (lane & 48) | (quad * 4 + r), 64);        \
        _Pragma("unroll") for (int ni = 0; ni < 4; ++ni)                       \
            o_acc[ni][r] *= alD;                                               \
      }                                                                        \
    }                                                                          \
    /* in-register rowsum: per-lane 16-sum + 2 shfl_xor -> replicated */       \
    {                                                                          \
      float t0 = (pf[0][0] + pf[0][1]) + (pf[0][2] + pf[0][3]);                \
      float t1 = (pf[1][0] + pf[1][1]) + (pf[1][2] + pf[1][3]);                \
      float t2 = (pf[2][0] + pf[2][1]) + (pf[2][2] + pf[2][3]);                \
      float t3 = (pf[3][0] + pf[3][1]) + (pf[3][2] + pf[3][3]);                \
      float ts = (t0 + t1) + (t2 + t3);                                        \
      ts += __shfl_xor(ts, 16, 64);                                            \
      ts += __shfl_xor(ts, 32, 64);                                            \
      l_s += ts;                                                               \
    }                                                                          \
    /* P -> bf16; 4 consecutive kv per (ni) -> one b64 store each */           \
    _Pragma("unroll") for (int ni = 0; ni < 4; ++ni) {                         \
      bf16x4 pk_;                                                              \
      _Pragma("unroll") for (int r = 0; r < 4; ++r)                            \
          pk_[r] = (bf16_t)pf[ni][r];                                          \
      *(bf16x4*)&PS[wave][(c * 8 + ((2 * ni + (quad >> 1)) ^ sw)) * 8 +        \
                          (quad & 1) * 4] = pk_;                               \
    }                                                                          \
    asm volatile("s_waitcnt lgkmcnt(0)" ::: "memory");                         \
    const bf16x8 p0 = *(const bf16x8*)&PS[wave][e0];                           \
    const bf16x8 p1 = *(const bf16x8*)&PS[wave][e1];                           \
    _Pragma("unroll") for (int ni = 0; ni < 4; ++ni) {                         \
      const bf16x8 v0 = *(const bf16x8*)&VtS[CUR][ni * 1024 + e0];             \
      const bf16x8 v1 = *(const bf16x8*)&VtS[CUR][ni * 1024 + e1];             \
      o_acc[ni] = MFMA16(p0, v0, o_acc[ni]);                                   \
      o_acc[ni] = MFMA16(p1, v1, o_acc[ni]);                                   \
    }                                                                          \
    if (fi_ == nA - 1) {                                                       \
      write_O(qtbase);                                                         \
      qtbase = qtB * 64;                                                       \
      qf0 = *(const bf16x8*)(Qh + (qtbase + wave * 16 + c) * DH + quad * 8);   \
      qf1 = *(const bf16x8*)(Qh + (qtbase + wave * 16 + c) * DH + 32 +         \
                             quad * 8);                                        \
      m_s = -1e30f;                                                            \
      l_s = 0.f;                                                               \
      _Pragma("unroll") for (int ni = 0; ni < 4; ++ni) o_acc[ni] = zero4;      \
    }                                                                          \
    if (pre_) store_tile(1 - (CUR));                                           \
    __syncthreads();                                                           \
    coff = noff_;                                                              \
    kkey = (fi_ + 1 == nA) ? 0 : kkey + 64;                                    \
  }

  for (int fj = 0; fj < 16; ++fj) {
    ATTN_ITER(2 * fj, 0)
    ATTN_ITER(2 * fj + 1, 1)
  }
  ATTN_ITER(32, 0)
#undef ATTN_ITER

  write_O(qtbase);  // phase B epilogue
}

// ---------------------------------------------------------------------------
extern "C" void kernel_launch(void* const* d_in, const int* in_sizes, int n_in,
                              void* d_out, int out_size, void* d_ws,
                              size_t ws_size, hipStream_t stream) {
  // Resolve inputs by unique element-count signature.
  const float *x = nullptr, *fcos = nullptr, *fsin = nullptr;
  const float *qkv_w = nullptr, *qkv_b = nullptr, *proj_w = nullptr, *proj_b = nullptr;
  for (int i = 0; i < n_in; ++i) {
    const int s = in_sizes[i];
    const float* p = (const float*)d_in[i];
    if (s == BB * TT * CC) x = p;                        // 8388608
    else if (s == TT * (DH / 2)) { if (!fcos) fcos = p; else fsin = p; }
    else if (s == NQKV * CC) qkv_w = p;                  // 3145728
    else if (s == NQKV) qkv_b = p;                       // 3072
    else if (s == CC * CC) proj_w = p;                   // 1048576
    else if (s == CC) proj_b = p;                        // 1024
    // mask (TT*TT) unused; causality is structural
  }

  const size_t NE = (size_t)BB * TT * CC;  // 8388608
  bf16_t* Qb = (bf16_t*)d_ws;
  bf16_t* Kb = Qb + NE;
  bf16_t* Vb = Kb + NE;
  bf16_t* Ob = Vb + NE;
  // dead-region reuse (all hazard-free under stream ordering):
  bf16_t* xb = Ob;                 // x_bf16 lives in Ob region until attn
  bf16_t* wqkvb = (bf16_t*)d_out;  // qkv_w bf16 in d_out until gemm3 writes it

  const int n0 = (int)NE, n1 = NQKV * CC, n2 = CC * CC;
  // proj_w bf16: tail of workspace if it fits (enables single fused convert
  // and drops the mid-pipeline cvt launch); else Qb region after attn.
  const bool bigws = ws_size >= (size_t)(4 * NE + (size_t)n2) * sizeof(bf16_t);
  bf16_t* wpb = bigws ? (Ob + NE) : Qb;

  if (bigws) {
    cvt3_k<<<dim3((n0 + n1 + n2) / 2048), 256, 0, stream>>>(
        x, xb, n0, qkv_w, wqkvb, n1, proj_w, wpb, n2);
  } else {
    cvt2_k<<<dim3((n0 + n1) / 2048), 256, 0, stream>>>(x, xb, n0, qkv_w, wqkvb,
                                                       n1);
  }

  // 1) qkv = x @ qkv_w^T + b, fused RoPE + head-split (+0.125*log2e into Q)
  gemm_k<0><<<dim3(NQKV / 128, (BB * TT) / 128), 256, 0, stream>>>(
      xb, wqkvb, qkv_b, fcos, fsin, (void*)Qb, Kb, Vb);
  // 2) causal flash attention -> Ob (B*T, C) bf16 (overwrites xb)
  attn_k<<<dim3(BB * HH * 16), 256, 0, stream>>>(Qb, Kb, Vb, Ob);
  // 3) out = Ob @ proj_w^T + proj_b (fp32)
  if (!bigws) {
    cvt_k<<<dim3(n2 / 2048), 256, 0, stream>>>(proj_w, wpb, n2);
  }
  gemm_k<1><<<dim3(CC / 128, (BB * TT) / 128), 256, 0, stream>>>(
      Ob, wpb, proj_b, nullptr, nullptr, d_out, nullptr, nullptr);
}

// Round 13
// 271.623 us; speedup vs baseline: 1.0352x; 1.0352x over previous
//
#include <hip/hip_runtime.h>
#include <stdint.h>

// Problem constants
#define BB 4
#define TT 2048
#define CC 1024
#define HH 16
#define DH 64
#define NQKV 3072

typedef __bf16 bf16_t;
typedef __attribute__((ext_vector_type(8))) __bf16 bf16x8;
typedef __attribute__((ext_vector_type(4))) __bf16 bf16x4;
typedef __attribute__((ext_vector_type(4))) float f32x4;

#define MFMA16(a, b, c) __builtin_amdgcn_mfma_f32_16x16x32_bf16((a), (b), (c), 0, 0, 0)

// async global->LDS, 16B per lane. LDS dest = wave-uniform base + lane*16.
__device__ __forceinline__ void gll16(const void* g, void* l) {
  typedef const __attribute__((address_space(1))) void* gp_t;
  typedef __attribute__((address_space(3))) void* lp_t;
  __builtin_amdgcn_global_load_lds((gp_t)(uintptr_t)g, (lp_t)(uintptr_t)l, 16, 0, 0);
}

__device__ __forceinline__ void cvt8(const float* src, bf16_t* dst) {
  const f32x4 a = *(const f32x4*)(src);
  const f32x4 b = *(const f32x4*)(src + 4);
  bf16x8 r;
  r[0] = (bf16_t)a[0]; r[1] = (bf16_t)a[1]; r[2] = (bf16_t)a[2]; r[3] = (bf16_t)a[3];
  r[4] = (bf16_t)b[0]; r[5] = (bf16_t)b[1]; r[6] = (bf16_t)b[2]; r[7] = (bf16_t)b[3];
  *(bf16x8*)dst = r;
}

// ---------------------------------------------------------------------------
// fp32 -> bf16 converts (n multiples of 2048)
// ---------------------------------------------------------------------------
__global__ __launch_bounds__(256) void cvt_k(const float* __restrict__ src,
                                             bf16_t* __restrict__ dst, int n) {
  const int i8 = (blockIdx.x * 256 + threadIdx.x) * 8;
  if (i8 < n) cvt8(src + i8, dst + i8);
}

__global__ __launch_bounds__(256) void cvt2_k(const float* __restrict__ s0,
                                              bf16_t* __restrict__ d0, int n0,
                                              const float* __restrict__ s1,
                                              bf16_t* __restrict__ d1, int n1) {
  int i8 = (blockIdx.x * 256 + threadIdx.x) * 8;
  if (i8 < n0) { cvt8(s0 + i8, d0 + i8); return; }
  i8 -= n0;
  if (i8 < n1) cvt8(s1 + i8, d1 + i8);
}

// three independent arrays, one launch (kernel-count reduction)
__global__ __launch_bounds__(256) void cvt3_k(
    const float* __restrict__ s0, bf16_t* __restrict__ d0, int n0,
    const float* __restrict__ s1, bf16_t* __restrict__ d1, int n1,
    const float* __restrict__ s2, bf16_t* __restrict__ d2, int n2) {
  int i8 = (blockIdx.x * 256 + threadIdx.x) * 8;
  if (i8 < n0) { cvt8(s0 + i8, d0 + i8); return; }
  i8 -= n0;
  if (i8 < n1) { cvt8(s1 + i8, d1 + i8); return; }
  i8 -= n1;
  if (i8 < n2) cvt8(s2 + i8, d2 + i8);
}

// ---------------------------------------------------------------------------
// GEMM (bf16 A, bf16 W): C[m][n] = sum_k A[m][k]*W[n][k] (+bias[n]); K=1024.
// R11-verified kernel (273.5us total — session best). Bracketing: deeper
// pipeline (R6), bigger tile (R1), persistence (R10) ALL regress vs this.
//   stage-ahead 2-phase: issue next BK=32 step's 4 gll16 into buf^1 BEFORE
//   computing buf[cur]; single vmcnt(0)+s_barrier after the compute phase
//   (drain sits a full compute phase after issue; cross-block TLP covers it).
//   XCD-chunked + within-XCD 4x4 supertile remap (FETCH 84->62MB).
// LDS XOR-swizzled: logical (row r, chunk cc) at slot r*4 + (cc ^ (r&3));
// gather permutes the per-lane global source.
// EPI==0: qkv epilogue (RoPE Q/K, 0.125*log2e folded into Q, scatter B,H,T,dh)
// EPI==1: bias epilogue into fp32 out0
// ---------------------------------------------------------------------------
template <int EPI>
__global__ __launch_bounds__(256) void gemm_k(
    const bf16_t* __restrict__ A, const bf16_t* __restrict__ W,
    const float* __restrict__ bias,
    const float* __restrict__ fcos, const float* __restrict__ fsin,
    void* __restrict__ out0v, bf16_t* __restrict__ out1,
    bf16_t* __restrict__ out2) {
  __shared__ bf16_t Alds[2][128 * 32];  // [dbuf][128 rows x 32 k]
  __shared__ bf16_t Blds[2][128 * 32];
  const int K = 1024;
  const int tid = threadIdx.x;
  const int lane = tid & 63, wave = tid >> 6;
  const int quad = lane >> 4, c = lane & 15;
  const int wm = wave >> 1, wn = wave & 1;

  // XCD-chunked + within-XCD 4x4 supertile remap (requires nx%4==0 and
  // (cpx/nx)%4==0; holds for both launches: 24x64 and 8x64).
  const int nx = gridDim.x;
  const int d = blockIdx.y * nx + blockIdx.x;  // dispatch order (x fastest)
  const int cpx = (nx * gridDim.y) >> 3;
  const int xcd = d & 7, j = d >> 3;
  const int nyl = cpx / nx;        // by-rows per XCD (8 in both gemms)
  const int stpr = nx >> 2;        // supertiles along bx
  const int st = j >> 4, wi = j & 15;
  const int bx = (st % stpr) * 4 + (wi & 3);
  const int by = xcd * nyl + (st / stpr) * 4 + (wi >> 2);
  const int mbase = by * 128, nbase = bx * 128;

  f32x4 acc[4][4];
#pragma unroll
  for (int i = 0; i < 4; ++i)
#pragma unroll
    for (int j2 = 0; j2 < 4; ++j2) acc[i][j2] = (f32x4){0.f, 0.f, 0.f, 0.f};

  // permuted gather: slot s=tid (+256) holds logical (r=s>>2, cc=(s&3)^(r&3))
  const int s0 = tid, s1 = tid + 256;
  const int r0 = s0 >> 2, cc0 = (s0 & 3) ^ (r0 & 3);
  const int r1 = s1 >> 2, cc1 = (s1 & 3) ^ (r1 & 3);
  const bf16_t* ag0 = A + (mbase + r0) * K + cc0 * 8;
  const bf16_t* ag1 = A + (mbase + r1) * K + cc1 * 8;
  const bf16_t* bg0 = W + (nbase + r0) * K + cc0 * 8;
  const bf16_t* bg1 = W + (nbase + r1) * K + cc1 * 8;

#define GSTAGE(BUF, KO)                        \
  {                                            \
    gll16(ag0 + (KO), &Alds[BUF][s0 * 8]);     \
    gll16(ag1 + (KO), &Alds[BUF][s1 * 8]);     \
    gll16(bg0 + (KO), &Blds[BUF][s0 * 8]);     \
    gll16(bg1 + (KO), &Blds[BUF][s1 * 8]);     \
  }

// One BK=32 step. CUR is a literal 0/1; STG gates stage+barrier (off on the
// final step). Stage for step KS+1 goes into buf CUR^1 (its readers finished
// before the previous step's barrier).
#define GSTEP(KS, CUR, STG)                                                    \
  {                                                                            \
    if (STG) GSTAGE((CUR) ^ 1, ((KS) + 1) * 32);                               \
    bf16x8 af[4], bfr[4];                                                      \
    _Pragma("unroll") for (int mi = 0; mi < 4; ++mi) {                         \
      const int row = wm * 64 + mi * 16 + c;                                   \
      af[mi] = *(const bf16x8*)&Alds[CUR][(row * 4 + (quad ^ (row & 3))) * 8]; \
    }                                                                          \
    _Pragma("unroll") for (int ni = 0; ni < 4; ++ni) {                         \
      const int row = wn * 64 + ni * 16 + c;                                   \
      bfr[ni] =                                                                \
          *(const bf16x8*)&Blds[CUR][(row * 4 + (quad ^ (row & 3))) * 8];      \
    }                                                                          \
    _Pragma("unroll") for (int mi = 0; mi < 4; ++mi)                           \
        _Pragma("unroll") for (int ni = 0; ni < 4; ++ni)                       \
            acc[mi][ni] = MFMA16(af[mi], bfr[ni], acc[mi][ni]);                \
    if (STG) {                                                                 \
      asm volatile("s_waitcnt vmcnt(0)" ::: "memory");                         \
      __builtin_amdgcn_s_barrier();                                            \
      asm volatile("" ::: "memory");                                           \
    }                                                                          \
  }

  // prologue: stage step 0, drain, barrier
  GSTAGE(0, 0);
  asm volatile("s_waitcnt vmcnt(0)" ::: "memory");
  __builtin_amdgcn_s_barrier();
  asm volatile("" ::: "memory");

  // steps 0..29 (15 unrolled pairs), then 30 (stages 31), then 31 (no stage)
  for (int fj = 0; fj < 15; ++fj) {
    GSTEP(2 * fj, 0, 1)
    GSTEP(2 * fj + 1, 1, 1)
  }
  GSTEP(30, 0, 1)
  GSTEP(31, 1, 0)
#undef GSTEP
#undef GSTAGE

  // epilogue. C/D layout: col = lane&15 (+16*ni), row = quad*4 + r (+16*mi)
  const float qscale = 0.18033688011112042f;  // 0.125 * log2(e)
#pragma unroll
  for (int mi = 0; mi < 4; ++mi) {
#pragma unroll
    for (int ni = 0; ni < 4; ++ni) {
      const int n = nbase + wn * 64 + ni * 16 + c;
      const float bv = bias[n];
#pragma unroll
      for (int r = 0; r < 4; ++r) {
        const int m = mbase + wm * 64 + mi * 16 + quad * 4 + r;
        float v = acc[mi][ni][r] + bv;
        if (EPI == 0) {
          bf16_t* out0 = (bf16_t*)out0v;
          const int sel = n >> 10;  // 0=q 1=k 2=v
          const int nl = n & 1023;
          const int h = nl >> 6, dd = nl & 63;
          const int b = m >> 11, t = m & 2047;
          const int dst = ((b * HH + h) * TT + t) * DH + dd;
          if (sel < 2) {
            const float pv = __shfl_xor(v, 1, 64);  // RoPE partner (col n^1)
            const int d2 = dd >> 1;
            const float cs = fcos[t * 32 + d2];
            const float sn = fsin[t * 32 + d2];
            float o = ((dd & 1) == 0) ? (v * cs - pv * sn) : (pv * sn + v * cs);
            if (sel == 0) {
              o *= qscale;
              out0[dst] = (bf16_t)o;
            } else {
              out1[dst] = (bf16_t)o;
            }
          } else {
            out2[dst] = (bf16_t)v;
          }
        } else {
          float* outf = (float*)out0v;
          outf[m * CC + n] = v;
        }
      }
    }
  }
}

// ---------------------------------------------------------------------------
// Flash attention, causal. Q pre-scaled by 0.125*log2(e) (exp2 domain).
// R5-verified (R11 config): SWAPPED QK^T (S^T = mfma(K, Q)) — lane owns one
// q-row, in-register row-max (15 fmax + 2 shfl), P store as 4 x ds_write_b64,
// scalar defer-max (THR=8) with shfl-broadcast rescale, MFMA rowsum (R12's
// in-register rowsum + speculative exp2 REVERTED: 273.5 -> 281.2us).
// Kept: XCD-chunked swizzle, no setprio, uniform-work causal pairing,
// dbuf kv loop.
// ---------------------------------------------------------------------------
__global__ __launch_bounds__(256, 4) void attn_k(const bf16_t* __restrict__ Q,
                                                 const bf16_t* __restrict__ Kv,
                                                 const bf16_t* __restrict__ V,
                                                 bf16_t* __restrict__ O) {
  __shared__ bf16_t KS[2][64 * 64];
  __shared__ bf16_t VtS[2][64 * 64];
  __shared__ bf16_t PS[4][16 * 64];

  const int tid = threadIdx.x;
  const int lane = tid & 63, wave = tid >> 6;
  const int quad = lane >> 4, c = lane & 15;
  // XCD-chunked bijective swizzle: 1024 blocks = 8 XCDs x 128; each XCD gets
  // 8 complete (b,h) groups -> 4 MB K/V working set = its L2.
  const int d0 = blockIdx.x;
  const int bi = (d0 & 7) * 128 + (d0 >> 3);
  const int pair = bi & 15, h = (bi >> 4) & 15, b = bi >> 8;
  const int qtA = pair, qtB = 31 - pair;
  const int nA = qtA + 1;  // kv tiles in phase A

  const bf16_t* Qh = Q + ((b * HH + h) * TT) * DH;
  const bf16_t* Kh = Kv + ((b * HH + h) * TT) * DH;
  const bf16_t* Vh = V + ((b * HH + h) * TT) * DH;

  const f32x4 zero4 = {0.f, 0.f, 0.f, 0.f};
  bf16x8 ones8;
#pragma unroll
  for (int i = 0; i < 8; ++i) ones8[i] = (bf16_t)1.0f;

  // staging bases (per-thread, loop-invariant)
  const int krow0 = tid >> 3, kc8 = tid & 7, krow1 = krow0 + 32;
  const bf16_t* kbase0 = Kh + krow0 * DH + kc8 * 8;
  const bf16_t* kbase1 = Kh + krow1 * DH + kc8 * 8;
  const int vsb = tid >> 2, vjp = tid & 3;
  const int vrg = vsb & 7, vc8 = vsb >> 3;
  const int vd0 = vc8 * 8 + vjp * 2, vd1 = vd0 + 1;
  const bf16_t* vbase = Vh + vrg * 8 * DH + vd0;

  // invariant swizzled fragment offsets (elements): row c, chunk (quad|quad+4)
  const int sw = c & 7;
  const int e0 = c * 64 + (quad ^ sw) * 8;
  const int e1 = c * 64 + ((quad + 4) ^ sw) * 8;

  bf16x8 kr0, kr1;
  uint32_t vr[8];
  auto load_tile = [&](int eoff) {
    kr0 = *(const bf16x8*)(kbase0 + eoff);
    kr1 = *(const bf16x8*)(kbase1 + eoff);
    const bf16_t* vp = vbase + eoff;
#pragma unroll
    for (int i = 0; i < 8; ++i) vr[i] = *(const uint32_t*)(vp + i * DH);
  };
  auto store_tile = [&](int buf) {
    *(bf16x8*)&KS[buf][(krow0 * 8 + (kc8 ^ (krow0 & 7))) * 8] = kr0;
    *(bf16x8*)&KS[buf][(krow1 * 8 + (kc8 ^ (krow1 & 7))) * 8] = kr1;
    union { bf16x8 v; uint16_t u[8]; } colA, colB;
#pragma unroll
    for (int i = 0; i < 8; ++i) {
      colA.u[i] = (uint16_t)(vr[i] & 0xffffu);
      colB.u[i] = (uint16_t)(vr[i] >> 16);
    }
    *(bf16x8*)&VtS[buf][(vd0 * 8 + (vrg ^ (vd0 & 7))) * 8] = colA.v;
    *(bf16x8*)&VtS[buf][(vd1 * 8 + (vrg ^ (vd1 & 7))) * 8] = colB.v;
  };

  // phase state (A first)
  int qtbase = qtA * 64;
  bf16x8 qf0 = *(const bf16x8*)(Qh + (qtbase + wave * 16 + c) * DH + quad * 8);
  bf16x8 qf1 = *(const bf16x8*)(Qh + (qtbase + wave * 16 + c) * DH + 32 + quad * 8);

  f32x4 o_acc[4] = {zero4, zero4, zero4, zero4};
  float m_s = -1e30f;                 // running max for q-row c (S^T layout)
  float l_r[4] = {0.f, 0.f, 0.f, 0.f};  // rowsum, D layout (q = quad*4+r)

  auto write_O = [&](int qtb) {
#pragma unroll
    for (int r = 0; r < 4; ++r) {
      const int qg = qtb + wave * 16 + quad * 4 + r;
      const float inv = 1.0f / l_r[r];
#pragma unroll
      for (int ni = 0; ni < 4; ++ni)
        O[(b * TT + qg) * CC + h * 64 + ni * 16 + c] =
            (bf16_t)(o_acc[ni][r] * inv);
    }
  };

  load_tile(0);
  store_tile(0);
  __syncthreads();
  int coff = 0;   // current tile element offset into K/V
  int kkey = 0;   // current tile key-index base

// one kv iteration; CUR is a literal 0/1 -> LDS addresses fold to constants
#define ATTN_ITER(FI, CUR)                                                     \
  {                                                                            \
    const int fi_ = (FI);                                                      \
    const bool pre_ = fi_ < 32;                                                \
    const int noff_ = (fi_ + 1 == nA) ? 0 : coff + 64 * DH;                    \
    if (pre_) load_tile(noff_);                                                \
    bf16x8 kf0[4], kf1[4];                                                     \
    _Pragma("unroll") for (int ni = 0; ni < 4; ++ni) {                         \
      kf0[ni] = *(const bf16x8*)&KS[CUR][ni * 1024 + e0];                      \
      kf1[ni] = *(const bf16x8*)&KS[CUR][ni * 1024 + e1];                      \
    }                                                                          \
    /* swapped: s[ni][r] = S[q = qtbase+wave*16+c][kv = kkey+ni*16+quad*4+r] */\
    f32x4 s[4];                                                                \
    _Pragma("unroll") for (int ni = 0; ni < 4; ++ni) {                         \
      f32x4 t = MFMA16(kf0[ni], qf0, zero4);                                   \
      t = MFMA16(kf1[ni], qf1, t);                                             \
      s[ni] = t;                                                               \
    }                                                                          \
    const int minq_ = qtbase + wave * 16;                                      \
    if (kkey + 63 > minq_) {                                                   \
      const int qg_ = minq_ + c;                                               \
      _Pragma("unroll") for (int ni = 0; ni < 4; ++ni)                         \
          _Pragma("unroll") for (int r = 0; r < 4; ++r) {                      \
        const int key_ = kkey + ni * 16 + quad * 4 + r;                        \
        if (key_ > qg_) s[ni][r] = -1e30f;                                     \
      }                                                                        \
    }                                                                          \
    /* row max: in-register tree + 2 shuffles across quads */                  \
    float a0_ = fmaxf(fmaxf(s[0][0], s[0][1]), fmaxf(s[0][2], s[0][3]));       \
    float a1_ = fmaxf(fmaxf(s[1][0], s[1][1]), fmaxf(s[1][2], s[1][3]));       \
    float a2_ = fmaxf(fmaxf(s[2][0], s[2][1]), fmaxf(s[2][2], s[2][3]));       \
    float a3_ = fmaxf(fmaxf(s[3][0], s[3][1]), fmaxf(s[3][2], s[3][3]));       \
    float mx = fmaxf(fmaxf(a0_, a1_), fmaxf(a2_, a3_));                        \
    mx = fmaxf(mx, __shfl_xor(mx, 16, 64));                                    \
    mx = fmaxf(mx, __shfl_xor(mx, 32, 64));                                    \
    /* defer-max (T13): rescale only if some row-max grew by >8 */             \
    if (__any(mx > m_s + 8.0f)) {                                              \
      const float mnew = fmaxf(m_s, mx);                                       \
      const float al = __builtin_amdgcn_exp2f(m_s - mnew);                     \
      m_s = mnew;                                                              \
      _Pragma("unroll") for (int r = 0; r < 4; ++r) {                          \
        const float alD = __shfl(al, (lane & 48) | (quad * 4 + r), 64);        \
        l_r[r] *= alD;                                                         \
        _Pragma("unroll") for (int ni = 0; ni < 4; ++ni)                       \
            o_acc[ni][r] *= alD;                                               \
      }                                                                        \
    }                                                                          \
    /* P = exp2(S - m); 4 consecutive kv per (ni) -> one b64 store each */     \
    _Pragma("unroll") for (int ni = 0; ni < 4; ++ni) {                         \
      bf16x4 pk_;                                                              \
      _Pragma("unroll") for (int r = 0; r < 4; ++r)                            \
          pk_[r] = (bf16_t)__builtin_amdgcn_exp2f(s[ni][r] - m_s);             \
      *(bf16x4*)&PS[wave][(c * 8 + ((2 * ni + (quad >> 1)) ^ sw)) * 8 +        \
                          (quad & 1) * 4] = pk_;                               \
    }                                                                          \
    asm volatile("s_waitcnt lgkmcnt(0)" ::: "memory");                         \
    const bf16x8 p0 = *(const bf16x8*)&PS[wave][e0];                           \
    const bf16x8 p1 = *(const bf16x8*)&PS[wave][e1];                           \
    f32x4 rs = MFMA16(p0, ones8, zero4);                                       \
    rs = MFMA16(p1, ones8, rs);                                                \
    _Pragma("unroll") for (int ni = 0; ni < 4; ++ni) {                         \
      const bf16x8 v0 = *(const bf16x8*)&VtS[CUR][ni * 1024 + e0];             \
      const bf16x8 v1 = *(const bf16x8*)&VtS[CUR][ni * 1024 + e1];             \
      o_acc[ni] = MFMA16(p0, v0, o_acc[ni]);                                   \
      o_acc[ni] = MFMA16(p1, v1, o_acc[ni]);                                   \
    }                                                                          \
    _Pragma("unroll") for (int r = 0; r < 4; ++r) l_r[r] += rs[r];             \
    if (fi_ == nA - 1) {                                                       \
      write_O(qtbase);                                                         \
      qtbase = qtB * 64;                                                       \
      qf0 = *(const bf16x8*)(Qh + (qtbase + wave * 16 + c) * DH + quad * 8);   \
      qf1 = *(const bf16x8*)(Qh + (qtbase + wave * 16 + c) * DH + 32 +         \
                             quad * 8);                                        \
      m_s = -1e30f;                                                            \
      _Pragma("unroll") for (int r = 0; r < 4; ++r) l_r[r] = 0.f;              \
      _Pragma("unroll") for (int ni = 0; ni < 4; ++ni) o_acc[ni] = zero4;      \
    }                                                                          \
    if (pre_) store_tile(1 - (CUR));                                           \
    __syncthreads();                                                           \
    coff = noff_;                                                              \
    kkey = (fi_ + 1 == nA) ? 0 : kkey + 64;                                    \
  }

  for (int fj = 0; fj < 16; ++fj) {
    ATTN_ITER(2 * fj, 0)
    ATTN_ITER(2 * fj + 1, 1)
  }
  ATTN_ITER(32, 0)
#undef ATTN_ITER

  write_O(qtbase);  // phase B epilogue
}

// ---------------------------------------------------------------------------
extern "C" void kernel_launch(void* const* d_in, const int* in_sizes, int n_in,
                              void* d_out, int out_size, void* d_ws,
                              size_t ws_size, hipStream_t stream) {
  // Resolve inputs by unique element-count signature.
  const float *x = nullptr, *fcos = nullptr, *fsin = nullptr;
  const float *qkv_w = nullptr, *qkv_b = nullptr, *proj_w = nullptr, *proj_b = nullptr;
  for (int i = 0; i < n_in; ++i) {
    const int s = in_sizes[i];
    const float* p = (const float*)d_in[i];
    if (s == BB * TT * CC) x = p;                        // 8388608
    else if (s == TT * (DH / 2)) { if (!fcos) fcos = p; else fsin = p; }
    else if (s == NQKV * CC) qkv_w = p;                  // 3145728
    else if (s == NQKV) qkv_b = p;                       // 3072
    else if (s == CC * CC) proj_w = p;                   // 1048576
    else if (s == CC) proj_b = p;                        // 1024
    // mask (TT*TT) unused; causality is structural
  }

  const size_t NE = (size_t)BB * TT * CC;  // 8388608
  bf16_t* Qb = (bf16_t*)d_ws;
  bf16_t* Kb = Qb + NE;
  bf16_t* Vb = Kb + NE;
  bf16_t* Ob = Vb + NE;
  // dead-region reuse (all hazard-free under stream ordering):
  bf16_t* xb = Ob;                 // x_bf16 lives in Ob region until attn
  bf16_t* wqkvb = (bf16_t*)d_out;  // qkv_w bf16 in d_out until gemm3 writes it

  const int n0 = (int)NE, n1 = NQKV * CC, n2 = CC * CC;
  // proj_w bf16: tail of workspace if it fits (enables single fused convert
  // and drops the mid-pipeline cvt launch); else Qb region after attn.
  const bool bigws = ws_size >= (size_t)(4 * NE + (size_t)n2) * sizeof(bf16_t);
  bf16_t* wpb = bigws ? (Ob + NE) : Qb;

  if (bigws) {
    cvt3_k<<<dim3((n0 + n1 + n2) / 2048), 256, 0, stream>>>(
        x, xb, n0, qkv_w, wqkvb, n1, proj_w, wpb, n2);
  } else {
    cvt2_k<<<dim3((n0 + n1) / 2048), 256, 0, stream>>>(x, xb, n0, qkv_w, wqkvb,
                                                       n1);
  }

  // 1) qkv = x @ qkv_w^T + b, fused RoPE + head-split (+0.125*log2e into Q)
  gemm_k<0><<<dim3(NQKV / 128, (BB * TT) / 128), 256, 0, stream>>>(
      xb, wqkvb, qkv_b, fcos, fsin, (void*)Qb, Kb, Vb);
  // 2) causal flash attention -> Ob (B*T, C) bf16 (overwrites xb)
  attn_k<<<dim3(BB * HH * 16), 256, 0, stream>>>(Qb, Kb, Vb, Ob);
  // 3) out = Ob @ proj_w^T + proj_b (fp32)
  if (!bigws) {
    cvt_k<<<dim3(n2 / 2048), 256, 0, stream>>>(proj_w, wpb, n2);
  }
  gemm_k<1><<<dim3(CC / 128, (BB * TT) / 128), 256, 0, stream>>>(
      Ob, wpb, proj_b, nullptr, nullptr, d_out, nullptr, nullptr);
}